// Round 5
// baseline (324.285 us; speedup 1.0000x reference)
//
#include <hip/hip_runtime.h>

// SparseLoRAMoE, expert-grouped, atomic-free.
// Round-5 delta: k2 redesigned to be REGISTER-MINIMAL. Rounds 3/4 tried to
// hold a 64-wide accumulator tile per wave (acc[64] + 16 wa float4 + x
// double-buffer ~190+ VGPRs) and lost twice to spills. New mapping:
// lane = (entry, rank): 4 entries x 16 ranks per wave, each lane computes the
// FULL K=2048 dot for its (entry,rank) -> 1 accumulator (4 component chains),
// ~24 VGPRs, no LDS, no barrier, no shuffle; lane's value IS acts[ent][rank].
//   x load  = 16-lane broadcast (4 distinct 16B/instr)
//   wa load = 16 row-lines reused 4 consecutive iters (L1-resident window)
// k3: bucket's acts (<=8KB) + tokens + routing staged in LDS once; inner loop
// is LDS-broadcast + FMA + coalesced store; s0/s1 evaluated sequentially to
// halve live regs (~70 < 128 cap at 4 waves/EU). Out written exactly once.
//   K1 (272 blocks): per-bucket scan of idxs, LDS counter, no global atomics.

#define NDIM   2048
#define RANK   16
#define NEXP   16
#define TOKENS 4096
#define CAP_E  768      // per-expert entries; mean 512, sd ~22 -> +11 sigma
#define CAP_P  64       // per-pair tokens;   mean 16,  sd ~4  -> +12 sigma
#define TILE_E 16       // entries per K2 block (4 waves x 4 entries)
#define ETILES (CAP_E / TILE_E)   // 48

#define DOT4(a, b) ((a).x*(b).x + (a).y*(b).y + (a).z*(b).z + (a).w*(b).w)

// ---------------- K1: bucketing, one block per bucket ----------------
__global__ __launch_bounds__(256) void k1_bucket(const int* __restrict__ idxs,
                                                 int* __restrict__ cntE,
                                                 int* __restrict__ cntP,
                                                 int* __restrict__ bucketE,
                                                 int* __restrict__ bucketP) {
    __shared__ int lcnt;
    const int bid = blockIdx.x;
    const int tid = threadIdx.x;
    if (tid == 0) lcnt = 0;
    __syncthreads();

    if (bid < NEXP) {                       // expert bucket: entries i with idxs[i]==e
        const int e = bid;
        const int4* p4 = (const int4*)idxs; // 8192 ints -> 2048 int4
        int* bk = bucketE + e * CAP_E;
        for (int i = tid; i < TOKENS * 2 / 4; i += 256) {
            int4 v = p4[i];
            if (v.x == e) { int p = atomicAdd(&lcnt, 1); if (p < CAP_E) bk[p] = 4*i+0; }
            if (v.y == e) { int p = atomicAdd(&lcnt, 1); if (p < CAP_E) bk[p] = 4*i+1; }
            if (v.z == e) { int p = atomicAdd(&lcnt, 1); if (p < CAP_E) bk[p] = 4*i+2; }
            if (v.w == e) { int p = atomicAdd(&lcnt, 1); if (p < CAP_E) bk[p] = 4*i+3; }
        }
        __syncthreads();
        if (tid == 0) cntE[e] = lcnt < CAP_E ? lcnt : CAP_E;
    } else {                                // pair bucket: tokens t with (e0,e1)==pb
        const int pb = bid - NEXP;
        const int e0 = pb >> 4, e1 = pb & (NEXP - 1);
        const int2* p2 = (const int2*)idxs;
        int* bk = bucketP + pb * CAP_P;
        for (int t = tid; t < TOKENS; t += 256) {
            int2 v = p2[t];
            if (v.x == e0 && v.y == e1) {
                int p = atomicAdd(&lcnt, 1);
                if (p < CAP_P) bk[p] = t;
            }
        }
        __syncthreads();
        if (tid == 0) cntP[pb] = lcnt < CAP_P ? lcnt : CAP_P;
    }
}

// ---------------- K2: stage A, lane = (entry, rank), 1 accumulator ----------------
__global__ __launch_bounds__(256) void k2_stage_a(const float* __restrict__ x,
                                                  const float* __restrict__ wa,
                                                  const int* __restrict__ cntE,
                                                  const int* __restrict__ bucketE,
                                                  float* __restrict__ acts) {
    const int e    = blockIdx.x & (NEXP - 1);
    const int tile = blockIdx.x >> 4;           // 0..ETILES-1
    int n = cntE[e];
    const int start = tile * TILE_E;
    int m = n - start;
    if (m <= 0) return;
    if (m > TILE_E) m = TILE_E;

    const int tid  = threadIdx.x;
    const int lane = tid & 63;
    const int wave = tid >> 6;
    const int egrp = lane >> 4;                 // entry within wave (0..3)
    const int rank = lane & 15;

    int eidx = wave * 4 + egrp;                 // entry within tile (0..15)
    if (eidx >= m) eidx = m - 1;                // duplicate last (same-value store)
    const int ent = bucketE[e * CAP_E + start + eidx];

    const float* xr = x  + (size_t)(ent >> 1) * NDIM;
    const float* wr = wa + ((size_t)e * RANK + rank) * NDIM;

    // 4 independent accumulator chains (break fmac latency), 1 logical acc.
    float ax = 0.f, ay = 0.f, az = 0.f, aw = 0.f;
    #pragma unroll 8
    for (int k = 0; k < NDIM; k += 4) {
        float4 xv = *(const float4*)(xr + k);   // 16-lane broadcast
        float4 wv = *(const float4*)(wr + k);   // per-rank row stream
        ax += xv.x * wv.x;
        ay += xv.y * wv.y;
        az += xv.z * wv.z;
        aw += xv.w * wv.w;
    }
    float v  = (ax + ay) + (az + aw);
    float sv = v / (1.f + __expf(-v));          // silu
    acts[(size_t)ent * RANK + rank] = sv;       // lane's value IS the output elem
}

// ---------------- K3: stage B, LDS-staged bucket, final store ----------------
__global__ __launch_bounds__(256, 4) void k3_stage_b(const float* __restrict__ routing,
                                                     const float* __restrict__ wb,
                                                     const int* __restrict__ cntP,
                                                     const int* __restrict__ bucketP,
                                                     const float* __restrict__ acts,
                                                     float* __restrict__ out) {
    const int pb  = blockIdx.x & (NEXP * NEXP - 1);
    const int dch = blockIdx.x >> 8;
    int m = cntP[pb];
    if (m <= 0) return;
    if (m > CAP_P) m = CAP_P;
    const int e0 = pb >> 4;
    const int e1 = pb & (NEXP - 1);
    const int d  = dch * 256 + threadIdx.x;
    const int tid = threadIdx.x;

    __shared__ float sacts[CAP_P][2 * RANK];    // 8 KB
    __shared__ float srout[CAP_P][2];
    __shared__ int   stok[CAP_P];

    const int* bp = bucketP + pb * CAP_P;
    if (tid < m) {
        int t = bp[tid];
        stok[tid] = t;
        srout[tid][0] = routing[2 * t];
        srout[tid][1] = routing[2 * t + 1];
    }
    __syncthreads();
    // stage acts[2t .. 2t+1][0..15] = 32 floats/token, coalesced by float4
    for (int idx = tid; idx < m * 8; idx += 256) {
        int tok = idx >> 3, q = idx & 7;
        float4 v = *(const float4*)(acts + (size_t)stok[tok] * 2 * RANK + q * 4);
        *(float4*)&sacts[tok][q * 4] = v;
    }
    __syncthreads();

    const float4* w0p = (const float4*)(wb + ((size_t)e0 * NDIM + d) * RANK);
    const float4* w1p = (const float4*)(wb + ((size_t)e1 * NDIM + d) * RANK);
    const float4 w00 = w0p[0], w01 = w0p[1], w02 = w0p[2], w03 = w0p[3];
    const float4 w10 = w1p[0], w11 = w1p[1], w12 = w1p[2], w13 = w1p[3];

    #pragma unroll 2
    for (int i = 0; i < m; i++) {
        const float4* a = (const float4*)sacts[i];      // LDS broadcast reads
        float4 A0 = a[0], A1 = a[1], A2 = a[2], A3 = a[3];
        float s0 = DOT4(w00, A0) + DOT4(w01, A1) + DOT4(w02, A2) + DOT4(w03, A3);
        float4 B0 = a[4], B1 = a[5], B2 = a[6], B3 = a[7];
        float s1 = DOT4(w10, B0) + DOT4(w11, B1) + DOT4(w12, B2) + DOT4(w13, B3);
        out[(size_t)stok[i] * NDIM + d] = 2.0f * (srout[i][0] * s0 + srout[i][1] * s1);
    }
}

extern "C" void kernel_launch(void* const* d_in, const int* in_sizes, int n_in,
                              void* d_out, int out_size, void* d_ws, size_t ws_size,
                              hipStream_t stream) {
    const float* x       = (const float*)d_in[0];
    const float* routing = (const float*)d_in[1];
    const int*   idxs    = (const int*)  d_in[2];
    const float* wa      = (const float*)d_in[3];
    const float* wb      = (const float*)d_in[4];
    float*       out     = (float*)d_out;

    // ws layout (bytes): [cntE 64][cntP @64][bucketE @2048 48KB]
    //                    [bucketP @51200 64KB][acts @116736 512KB]
    int*   cntE    = (int*)d_ws;
    int*   cntP    = (int*)((char*)d_ws + 64);
    int*   bucketE = (int*)((char*)d_ws + 2048);
    int*   bucketP = (int*)((char*)d_ws + 2048 + NEXP * CAP_E * 4);
    float* acts    = (float*)((char*)d_ws + 2048 + NEXP * CAP_E * 4
                                          + NEXP * NEXP * CAP_P * 4);

    k1_bucket <<<NEXP + NEXP * NEXP, 256, 0, stream>>>(idxs, cntE, cntP, bucketE, bucketP);
    k2_stage_a<<<NEXP * ETILES, 256, 0, stream>>>(x, wa, cntE, bucketE, acts);
    k3_stage_b<<<NEXP * NEXP * (NDIM / 256), 256, 0, stream>>>(routing, wb, cntP,
                                                               bucketP, acts, out);
}

// Round 6
// 155.755 us; speedup vs baseline: 2.0820x; 2.0820x over previous
//
#include <hip/hip_runtime.h>

// SparseLoRAMoE, expert-grouped, atomic-free.
// Round-6 delta: k2 back to COALESCED lane-splits-K (round-5's lane=(entry,rank)
// mapping made every wa load touch 16 distinct cache lines -> TA serialization,
// 215us, VALUBusy 5.7%). Middle ground between r3 (acc[64], spilled) and r5
// (acc[1], uncoalesced): wave owns 2 entries x 16 ranks = acc[32]; rank-chunked
// inner loop keeps only 4 wa float4 live (~70 live VGPRs < 128 cap at (256,4)).
//   K2 (1536 blocks, 8 entries/block): lanes split K (fully coalesced); per
//   k-step: 2 x loads + 16 wa loads, 64 DOT4s; 64-lane halving butterfly
//   distributes results: lane<32 holds (entry lane>>4, rank lane&15).
//   K1 (272 blocks): per-bucket scan of idxs, LDS counter, no global atomics.
//   K3 (2048 blocks): bucket acts/routing/tokens staged in LDS; wb cols of both
//   experts in 32 VGPRs; final out written exactly once, coalesced.
// No zeroing, no global atomics on out, bit-deterministic output.

#define NDIM   2048
#define RANK   16
#define NEXP   16
#define TOKENS 4096
#define CAP_E  768      // per-expert entries; mean 512, sd ~22 -> +11 sigma
#define CAP_P  64       // per-pair tokens;   mean 16,  sd ~4  -> +12 sigma
#define TILE_E 8        // entries per K2 block (4 waves x 2)
#define ETILES (CAP_E / TILE_E)   // 96

#define DOT4(a, b) ((a).x*(b).x + (a).y*(b).y + (a).z*(b).z + (a).w*(b).w)

// ---------------- K1: bucketing, one block per bucket ----------------
__global__ __launch_bounds__(256) void k1_bucket(const int* __restrict__ idxs,
                                                 int* __restrict__ cntE,
                                                 int* __restrict__ cntP,
                                                 int* __restrict__ bucketE,
                                                 int* __restrict__ bucketP) {
    __shared__ int lcnt;
    const int bid = blockIdx.x;
    const int tid = threadIdx.x;
    if (tid == 0) lcnt = 0;
    __syncthreads();

    if (bid < NEXP) {                       // expert bucket: entries i with idxs[i]==e
        const int e = bid;
        const int4* p4 = (const int4*)idxs; // 8192 ints -> 2048 int4
        int* bk = bucketE + e * CAP_E;
        for (int i = tid; i < TOKENS * 2 / 4; i += 256) {
            int4 v = p4[i];
            if (v.x == e) { int p = atomicAdd(&lcnt, 1); if (p < CAP_E) bk[p] = 4*i+0; }
            if (v.y == e) { int p = atomicAdd(&lcnt, 1); if (p < CAP_E) bk[p] = 4*i+1; }
            if (v.z == e) { int p = atomicAdd(&lcnt, 1); if (p < CAP_E) bk[p] = 4*i+2; }
            if (v.w == e) { int p = atomicAdd(&lcnt, 1); if (p < CAP_E) bk[p] = 4*i+3; }
        }
        __syncthreads();
        if (tid == 0) cntE[e] = lcnt < CAP_E ? lcnt : CAP_E;
    } else {                                // pair bucket: tokens t with (e0,e1)==pb
        const int pb = bid - NEXP;
        const int e0 = pb >> 4, e1 = pb & (NEXP - 1);
        const int2* p2 = (const int2*)idxs;
        int* bk = bucketP + pb * CAP_P;
        for (int t = tid; t < TOKENS; t += 256) {
            int2 v = p2[t];
            if (v.x == e0 && v.y == e1) {
                int p = atomicAdd(&lcnt, 1);
                if (p < CAP_P) bk[p] = t;
            }
        }
        __syncthreads();
        if (tid == 0) cntP[pb] = lcnt < CAP_P ? lcnt : CAP_P;
    }
}

// ---------------- K2: stage A, coalesced, acc[32], no LDS/barriers ----------------
__global__ __launch_bounds__(256, 4) void k2_stage_a(const float* __restrict__ x,
                                                     const float* __restrict__ wa,
                                                     const int* __restrict__ cntE,
                                                     const int* __restrict__ bucketE,
                                                     float* __restrict__ acts) {
    const int e    = blockIdx.x & (NEXP - 1);
    const int tile = blockIdx.x >> 4;           // 0..ETILES-1
    const int n    = cntE[e];
    const int start = tile * TILE_E;
    if (start >= n) return;

    const int tid  = threadIdx.x;
    const int lane = tid & 63;
    const int wave = tid >> 6;

    int i0 = start + wave * 2 + 0; if (i0 >= n) i0 = n - 1;   // tail: duplicate
    int i1 = start + wave * 2 + 1; if (i1 >= n) i1 = n - 1;   // (same-value store)
    const int ent0 = bucketE[e * CAP_E + i0];
    const int ent1 = bucketE[e * CAP_E + i1];

    const float* x0 = x + (size_t)(ent0 >> 1) * NDIM + lane * 4;
    const float* x1 = x + (size_t)(ent1 >> 1) * NDIM + lane * 4;
    const float* wr = wa + (size_t)e * RANK * NDIM + lane * 4;

    float acc[32];
    #pragma unroll
    for (int i = 0; i < 32; i++) acc[i] = 0.f;

    for (int s = 0; s < NDIM / 256; s++) {      // 8 steps, lanes split K
        const int off = s * 256;
        float4 xv0 = *(const float4*)(x0 + off);
        float4 xv1 = *(const float4*)(x1 + off);
        #pragma unroll
        for (int r4 = 0; r4 < RANK; r4 += 4) {  // 4 wa float4 live at a time
            float4 w0 = *(const float4*)(wr + (r4 + 0) * NDIM + off);
            float4 w1 = *(const float4*)(wr + (r4 + 1) * NDIM + off);
            float4 w2 = *(const float4*)(wr + (r4 + 2) * NDIM + off);
            float4 w3 = *(const float4*)(wr + (r4 + 3) * NDIM + off);
            acc[r4 + 0]      += DOT4(xv0, w0);
            acc[r4 + 1]      += DOT4(xv0, w1);
            acc[r4 + 2]      += DOT4(xv0, w2);
            acc[r4 + 3]      += DOT4(xv0, w3);
            acc[16 + r4 + 0] += DOT4(xv1, w0);
            acc[16 + r4 + 1] += DOT4(xv1, w1);
            acc[16 + r4 + 2] += DOT4(xv1, w2);
            acc[16 + r4 + 3] += DOT4(xv1, w3);
        }
    }

    // ---- 64-lane reduce + distribute: lane<32 -> (entry lane>>4, rank lane&15)
    #pragma unroll
    for (int i = 0; i < 32; i++) acc[i] += __shfl_xor(acc[i], 32, 64);
    {   // mw=16: split entry bit across lane bit 4
        const bool up = (lane & 16) != 0;
        #pragma unroll
        for (int i = 0; i < 16; i++) {
            float lo = acc[i], hi = acc[i + 16];
            float mine = up ? hi : lo;
            float give = up ? lo : hi;
            acc[i] = mine + __shfl_xor(give, 16, 64);
        }
    }
    #pragma unroll
    for (int mw = 8; mw >= 1; mw >>= 1) {       // split rank bits
        const bool up = (lane & mw) != 0;
        #pragma unroll
        for (int i = 0; i < mw; i++) {
            float lo = acc[i], hi = acc[i + mw];
            float mine = up ? hi : lo;
            float give = up ? lo : hi;
            acc[i] = mine + __shfl_xor(give, mw, 64);
        }
    }
    if (lane < 32) {
        float v  = acc[0];
        float sv = v / (1.f + __expf(-v));      // silu
        int ent  = (lane < 16) ? ent0 : ent1;
        acts[(size_t)ent * RANK + (lane & 15)] = sv;
    }
}

// ---------------- K3: stage B, LDS-staged bucket, final store ----------------
__global__ __launch_bounds__(256, 4) void k3_stage_b(const float* __restrict__ routing,
                                                     const float* __restrict__ wb,
                                                     const int* __restrict__ cntP,
                                                     const int* __restrict__ bucketP,
                                                     const float* __restrict__ acts,
                                                     float* __restrict__ out) {
    const int pb  = blockIdx.x & (NEXP * NEXP - 1);
    const int dch = blockIdx.x >> 8;
    int m = cntP[pb];
    if (m <= 0) return;
    if (m > CAP_P) m = CAP_P;
    const int e0 = pb >> 4;
    const int e1 = pb & (NEXP - 1);
    const int d  = dch * 256 + threadIdx.x;
    const int tid = threadIdx.x;

    __shared__ float sacts[CAP_P][2 * RANK];    // 8 KB
    __shared__ float srout[CAP_P][2];
    __shared__ int   stok[CAP_P];

    const int* bp = bucketP + pb * CAP_P;
    if (tid < m) {
        int t = bp[tid];
        stok[tid] = t;
        srout[tid][0] = routing[2 * t];
        srout[tid][1] = routing[2 * t + 1];
    }
    __syncthreads();
    for (int idx = tid; idx < m * 8; idx += 256) {
        int tok = idx >> 3, q = idx & 7;
        float4 v = *(const float4*)(acts + (size_t)stok[tok] * 2 * RANK + q * 4);
        *(float4*)&sacts[tok][q * 4] = v;
    }
    __syncthreads();

    const float4* w0p = (const float4*)(wb + ((size_t)e0 * NDIM + d) * RANK);
    const float4* w1p = (const float4*)(wb + ((size_t)e1 * NDIM + d) * RANK);
    const float4 w00 = w0p[0], w01 = w0p[1], w02 = w0p[2], w03 = w0p[3];
    const float4 w10 = w1p[0], w11 = w1p[1], w12 = w1p[2], w13 = w1p[3];

    #pragma unroll 2
    for (int i = 0; i < m; i++) {
        const float4* a = (const float4*)sacts[i];      // LDS broadcast reads
        float4 A0 = a[0], A1 = a[1], A2 = a[2], A3 = a[3];
        float s0 = DOT4(w00, A0) + DOT4(w01, A1) + DOT4(w02, A2) + DOT4(w03, A3);
        float4 B0 = a[4], B1 = a[5], B2 = a[6], B3 = a[7];
        float s1 = DOT4(w10, B0) + DOT4(w11, B1) + DOT4(w12, B2) + DOT4(w13, B3);
        out[(size_t)stok[i] * NDIM + d] = 2.0f * (srout[i][0] * s0 + srout[i][1] * s1);
    }
}

extern "C" void kernel_launch(void* const* d_in, const int* in_sizes, int n_in,
                              void* d_out, int out_size, void* d_ws, size_t ws_size,
                              hipStream_t stream) {
    const float* x       = (const float*)d_in[0];
    const float* routing = (const float*)d_in[1];
    const int*   idxs    = (const int*)  d_in[2];
    const float* wa      = (const float*)d_in[3];
    const float* wb      = (const float*)d_in[4];
    float*       out     = (float*)d_out;

    // ws layout (bytes): [cntE 64][cntP @64][bucketE @2048 48KB]
    //                    [bucketP @51200 64KB][acts @116736 512KB]
    int*   cntE    = (int*)d_ws;
    int*   cntP    = (int*)((char*)d_ws + 64);
    int*   bucketE = (int*)((char*)d_ws + 2048);
    int*   bucketP = (int*)((char*)d_ws + 2048 + NEXP * CAP_E * 4);
    float* acts    = (float*)((char*)d_ws + 2048 + NEXP * CAP_E * 4
                                          + NEXP * NEXP * CAP_P * 4);

    k1_bucket <<<NEXP + NEXP * NEXP, 256, 0, stream>>>(idxs, cntE, cntP, bucketE, bucketP);
    k2_stage_a<<<NEXP * ETILES, 256, 0, stream>>>(x, wa, cntE, bucketE, acts);
    k3_stage_b<<<NEXP * NEXP * (NDIM / 256), 256, 0, stream>>>(routing, wb, cntP,
                                                               bucketP, acts, out);
}

// Round 7
// 127.429 us; speedup vs baseline: 2.5448x; 1.2223x over previous
//
#include <hip/hip_runtime.h>

// SparseLoRAMoE, expert-grouped, atomic-free.
// Round-7: REVERT k2 to the round-4 structure (best measured, <=41us):
// wave owns 4 entries x 16 ranks (acc[64]), lanes split K (fully coalesced),
// issue all 16 wa row-loads then consume (progressive vmcnt), x prefetched one
// step ahead, __launch_bounds__(256,2) -> 256-VGPR cap, no spill (~178 live).
// Round-6's E=2 halved arithmetic intensity to L1 (3.6 vs 6.4 flop/float) and
// regressed to 57us; E=4 is the sweet spot of the L1 wall vs register wall.
// k3: each thread now covers TWO columns (d, d+256) -> wb L2 traffic halved
// (8x -> 4x re-read per pair), LDS-staged bucket amortized over 2x FMA, and
// non-temporal final stores keep `out` from polluting L2.
//   K1 (272 blocks): per-bucket scan of idxs, LDS counter, no global atomics.
// No zeroing, no global atomics on out, bit-deterministic output.

#define NDIM   2048
#define RANK   16
#define NEXP   16
#define TOKENS 4096
#define CAP_E  768      // per-expert entries; mean 512, sd ~22 -> +11 sigma
#define CAP_P  64       // per-pair tokens;   mean 16,  sd ~4  -> +12 sigma
#define TILE_E 16       // entries per K2 block (4 waves x 4)
#define ETILES (CAP_E / TILE_E)   // 48

#define DOT4(a, b) ((a).x*(b).x + (a).y*(b).y + (a).z*(b).z + (a).w*(b).w)

// ---------------- K1: bucketing, one block per bucket ----------------
__global__ __launch_bounds__(256) void k1_bucket(const int* __restrict__ idxs,
                                                 int* __restrict__ cntE,
                                                 int* __restrict__ cntP,
                                                 int* __restrict__ bucketE,
                                                 int* __restrict__ bucketP) {
    __shared__ int lcnt;
    const int bid = blockIdx.x;
    const int tid = threadIdx.x;
    if (tid == 0) lcnt = 0;
    __syncthreads();

    if (bid < NEXP) {                       // expert bucket: entries i with idxs[i]==e
        const int e = bid;
        const int4* p4 = (const int4*)idxs; // 8192 ints -> 2048 int4
        int* bk = bucketE + e * CAP_E;
        for (int i = tid; i < TOKENS * 2 / 4; i += 256) {
            int4 v = p4[i];
            if (v.x == e) { int p = atomicAdd(&lcnt, 1); if (p < CAP_E) bk[p] = 4*i+0; }
            if (v.y == e) { int p = atomicAdd(&lcnt, 1); if (p < CAP_E) bk[p] = 4*i+1; }
            if (v.z == e) { int p = atomicAdd(&lcnt, 1); if (p < CAP_E) bk[p] = 4*i+2; }
            if (v.w == e) { int p = atomicAdd(&lcnt, 1); if (p < CAP_E) bk[p] = 4*i+3; }
        }
        __syncthreads();
        if (tid == 0) cntE[e] = lcnt < CAP_E ? lcnt : CAP_E;
    } else {                                // pair bucket: tokens t with (e0,e1)==pb
        const int pb = bid - NEXP;
        const int e0 = pb >> 4, e1 = pb & (NEXP - 1);
        const int2* p2 = (const int2*)idxs;
        int* bk = bucketP + pb * CAP_P;
        for (int t = tid; t < TOKENS; t += 256) {
            int2 v = p2[t];
            if (v.x == e0 && v.y == e1) {
                int p = atomicAdd(&lcnt, 1);
                if (p < CAP_P) bk[p] = t;
            }
        }
        __syncthreads();
        if (tid == 0) cntP[pb] = lcnt < CAP_P ? lcnt : CAP_P;
    }
}

// ---------------- K2: stage A (round-4 structure), E=4, x double-buffered ----------------
__global__ __launch_bounds__(256, 2) void k2_stage_a(const float* __restrict__ x,
                                                     const float* __restrict__ wa,
                                                     const int* __restrict__ cntE,
                                                     const int* __restrict__ bucketE,
                                                     float* __restrict__ acts) {
    const int e    = blockIdx.x & (NEXP - 1);
    const int tile = blockIdx.x >> 4;           // 0..ETILES-1
    int n = cntE[e];
    const int start = tile * TILE_E;
    int m = n - start;
    if (m <= 0) return;
    if (m > TILE_E) m = TILE_E;

    __shared__ int sTok[TILE_E];
    const int tid  = threadIdx.x;
    const int lane = tid & 63;
    const int wave = tid >> 6;

    if (tid < TILE_E) {
        int src = tid < m ? tid : m - 1;        // duplicate last entry in short tiles
        sTok[tid] = bucketE[e * CAP_E + start + src];
    }
    __syncthreads();                            // the only barrier in this kernel

    // wave owns entries wave*4 .. wave*4+3; lanes split K (16B each)
    const float* xp[4];
    #pragma unroll
    for (int j = 0; j < 4; j++)
        xp[j] = x + (size_t)(sTok[wave * 4 + j] >> 1) * NDIM + lane * 4;
    const float* wbase = wa + (size_t)e * RANK * NDIM + lane * 4;

    float acc[64];
    #pragma unroll
    for (int i = 0; i < 64; i++) acc[i] = 0.f;

    float4 xc[4], xn[4];
    #pragma unroll
    for (int j = 0; j < 4; j++) xc[j] = *(const float4*)(xp[j]);

    #pragma unroll 2
    for (int s = 0; s < NDIM / 256; s++) {      // 8 steps of 256 floats
        if (s < NDIM / 256 - 1) {               // prefetch next x step (HBM stream)
            #pragma unroll
            for (int j = 0; j < 4; j++)
                xn[j] = *(const float4*)(xp[j] + (s + 1) * 256);
        }
        const float* wstep = wbase + s * 256;
        float4 wv[16];
        #pragma unroll
        for (int r = 0; r < RANK; r++)          // issue all 16 wa loads...
            wv[r] = *(const float4*)(wstep + r * NDIM);
        #pragma unroll
        for (int r = 0; r < RANK; r++) {        // ...consume in order (progressive vmcnt)
            acc[r]      += DOT4(xc[0], wv[r]);
            acc[16 + r] += DOT4(xc[1], wv[r]);
            acc[32 + r] += DOT4(xc[2], wv[r]);
            acc[48 + r] += DOT4(xc[3], wv[r]);
        }
        #pragma unroll
        for (int j = 0; j < 4; j++) xc[j] = xn[j];
    }

    // 64-value -> per-lane halving butterfly (all static indices, stays in VGPRs)
    #pragma unroll
    for (int mw = 32; mw >= 1; mw >>= 1) {
        const bool up = (lane & mw) != 0;
        #pragma unroll
        for (int i = 0; i < mw; i++) {
            float lo = acc[i], hi = acc[i + mw];
            float mine = up ? hi : lo;
            float give = up ? lo : hi;
            acc[i] = mine + __shfl_xor(give, mw, 64);
        }
    }
    // lane l holds dot for entry sTok[wave*4 + (l>>4)], rank l&15
    float v  = acc[0];
    float sv = v / (1.f + __expf(-v));          // silu
    int ent  = sTok[(wave << 2) + (lane >> 4)];
    acts[(size_t)ent * RANK + (lane & 15)] = sv;
}

// ---------------- K3: stage B, 2 cols/thread, LDS-staged bucket, NT stores ----------------
__global__ __launch_bounds__(256, 2) void k3_stage_b(const float* __restrict__ routing,
                                                     const float* __restrict__ wb,
                                                     const int* __restrict__ cntP,
                                                     const int* __restrict__ bucketP,
                                                     const float* __restrict__ acts,
                                                     float* __restrict__ out) {
    const int pb  = blockIdx.x & (NEXP * NEXP - 1);
    const int dch = blockIdx.x >> 8;            // 0..3 (512 cols per block)
    int m = cntP[pb];
    if (m <= 0) return;
    if (m > CAP_P) m = CAP_P;
    const int e0 = pb >> 4;
    const int e1 = pb & (NEXP - 1);
    const int tid = threadIdx.x;
    const int d0 = dch * 512 + tid;
    const int d1 = d0 + 256;

    __shared__ float sacts[CAP_P][2 * RANK];    // 8 KB
    __shared__ float srout[CAP_P][2];
    __shared__ int   stok[CAP_P];

    const int* bp = bucketP + pb * CAP_P;
    if (tid < m) {
        int t = bp[tid];
        stok[tid] = t;
        srout[tid][0] = routing[2 * t];
        srout[tid][1] = routing[2 * t + 1];
    }
    __syncthreads();
    for (int idx = tid; idx < m * 8; idx += 256) {
        int tok = idx >> 3, q = idx & 7;
        float4 v = *(const float4*)(acts + (size_t)stok[tok] * 2 * RANK + q * 4);
        *(float4*)&sacts[tok][q * 4] = v;
    }
    __syncthreads();

    // wb cols for BOTH experts at BOTH d0,d1: 16 float4 = 64 VGPRs, reused over bucket
    const float4* p00 = (const float4*)(wb + ((size_t)e0 * NDIM + d0) * RANK);
    const float4* p01 = (const float4*)(wb + ((size_t)e0 * NDIM + d1) * RANK);
    const float4* p10 = (const float4*)(wb + ((size_t)e1 * NDIM + d0) * RANK);
    const float4* p11 = (const float4*)(wb + ((size_t)e1 * NDIM + d1) * RANK);
    const float4 a00 = p00[0], a01 = p00[1], a02 = p00[2], a03 = p00[3];
    const float4 b00 = p01[0], b01 = p01[1], b02 = p01[2], b03 = p01[3];
    const float4 a10 = p10[0], a11 = p10[1], a12 = p10[2], a13 = p10[3];
    const float4 b10 = p11[0], b11 = p11[1], b12 = p11[2], b13 = p11[3];

    #pragma unroll 2
    for (int i = 0; i < m; i++) {
        const float4* a = (const float4*)sacts[i];      // LDS broadcast reads
        float4 A0 = a[0], A1 = a[1], A2 = a[2], A3 = a[3];
        float4 B0 = a[4], B1 = a[5], B2 = a[6], B3 = a[7];
        float s0_0 = DOT4(a00, A0) + DOT4(a01, A1) + DOT4(a02, A2) + DOT4(a03, A3);
        float s1_0 = DOT4(a10, B0) + DOT4(a11, B1) + DOT4(a12, B2) + DOT4(a13, B3);
        float s0_1 = DOT4(b00, A0) + DOT4(b01, A1) + DOT4(b02, A2) + DOT4(b03, A3);
        float s1_1 = DOT4(b10, B0) + DOT4(b11, B1) + DOT4(b12, B2) + DOT4(b13, B3);
        const float r0 = srout[i][0], r1 = srout[i][1];
        float* op = out + (size_t)stok[i] * NDIM;
        __builtin_nontemporal_store(2.0f * (r0 * s0_0 + r1 * s1_0), op + d0);
        __builtin_nontemporal_store(2.0f * (r0 * s0_1 + r1 * s1_1), op + d1);
    }
}

extern "C" void kernel_launch(void* const* d_in, const int* in_sizes, int n_in,
                              void* d_out, int out_size, void* d_ws, size_t ws_size,
                              hipStream_t stream) {
    const float* x       = (const float*)d_in[0];
    const float* routing = (const float*)d_in[1];
    const int*   idxs    = (const int*)  d_in[2];
    const float* wa      = (const float*)d_in[3];
    const float* wb      = (const float*)d_in[4];
    float*       out     = (float*)d_out;

    // ws layout (bytes): [cntE 64][cntP @64][bucketE @2048 48KB]
    //                    [bucketP @51200 64KB][acts @116736 512KB]
    int*   cntE    = (int*)d_ws;
    int*   cntP    = (int*)((char*)d_ws + 64);
    int*   bucketE = (int*)((char*)d_ws + 2048);
    int*   bucketP = (int*)((char*)d_ws + 2048 + NEXP * CAP_E * 4);
    float* acts    = (float*)((char*)d_ws + 2048 + NEXP * CAP_E * 4
                                          + NEXP * NEXP * CAP_P * 4);

    k1_bucket <<<NEXP + NEXP * NEXP, 256, 0, stream>>>(idxs, cntE, cntP, bucketE, bucketP);
    k2_stage_a<<<NEXP * ETILES, 256, 0, stream>>>(x, wa, cntE, bucketE, acts);
    k3_stage_b<<<NEXP * NEXP * (NDIM / 512), 256, 0, stream>>>(routing, wb, cntP,
                                                               bucketP, acts, out);
}